// Round 4
// baseline (135.366 us; speedup 1.0000x reference)
//
#include <hip/hip_runtime.h>
#include <stdint.h>

// ContrastiveLoss: B=64, N=1024, D=128.
// loss = (1/count) * sum_b valid_b * sum_{i pos} mean_{j neg} relu(<e_i,e_j> - 0.15)
//
// R3 lesson: dur_us includes ~52us of harness restore/poison (256MiB ws fill
// at 6 TB/s shows as top dispatch every round); kernel budget ~47us.
// R4: fp8-e4m3 compacted arrays (HW RNE cvt; halves all staging traffic),
// early-exit all-zero pad tiles, finalize fused into gemm via atomic ticket.
// Pipeline: scan -> prep(gather,fp8) -> gemm(+finalize). 3 dispatches.

#define B_    64
#define N_    1024
#define D_    128
#define NPAD  640          // 5 tiles of 128; npos~Binom(1024,.5), 640 = +8 sigma
#define T_    5            // tiles per side
#define NTILE (T_ * T_)
#define NBLK  (T_ * T_ * B_)

typedef __attribute__((ext_vector_type(4))) float floatx4;
typedef __attribute__((ext_vector_type(4))) unsigned short ushortx4;

// ---------- scan: per-batch prefix sums of labels -> compaction maps ----------
__global__ __launch_bounds__(256) void scan_kernel(
    const long long* __restrict__ lab,
    unsigned short* __restrict__ posIdx,   // [B_][NPAD]
    unsigned short* __restrict__ negIdx,   // [B_][NPAD]
    int* __restrict__ npos,                // [B_]
    int* __restrict__ counter)             // ticket counter for gemm finalize
{
    __shared__ int wsum[4];
    const int b = blockIdx.x, t = threadIdx.x;
    const int w = t >> 6, lane = t & 63;
    if (b == 0 && t == 0) *counter = 0;    // reset each launch (ws is poisoned)
    const long long* lb = lab + (size_t)b * N_;

    int l[4], c = 0;
    #pragma unroll
    for (int i = 0; i < 4; ++i) { l[i] = (int)lb[t * 4 + i]; c += l[i]; }

    int sc = c;                              // inclusive wave scan
    #pragma unroll
    for (int off = 1; off < 64; off <<= 1) {
        int v = __shfl_up(sc, off);
        if (lane >= off) sc += v;
    }
    if (lane == 63) wsum[w] = sc;
    __syncthreads();
    int base = 0;
    for (int k = 0; k < w; ++k) base += wsum[k];

    int pe = base + sc - c;                  // pos count in [0, t*4)
    #pragma unroll
    for (int i = 0; i < 4; ++i) {
        const int n = t * 4 + i;
        if (l[i]) { if (pe < NPAD) posIdx[b * NPAD + pe] = (unsigned short)n; }
        else      { const int ne = n - pe; if (ne < NPAD) negIdx[b * NPAD + ne] = (unsigned short)n; }
        pe += l[i];
    }
    if (t == 255) npos[b] = base + sc;
}

// ---------- prep: gather + L2-normalize + fp8(e4m3, RNE) pack ----------
// One wave handles TWO slots (lanes 0-31 / 32-63), float4 loads, 4B fp8 out.
__global__ __launch_bounds__(256) void prep_kernel(
    const float* __restrict__ emb,
    const unsigned short* __restrict__ posIdx,
    const unsigned short* __restrict__ negIdx,
    const int* __restrict__ npos,
    unsigned int* __restrict__ Apos_c,       // [B_*NPAD*D_] fp8 as packed u32
    unsigned int* __restrict__ Aneg_c)
{
    const int w    = threadIdx.x >> 6;
    const int lane = threadIdx.x & 63;
    const int gw   = blockIdx.x * 4 + w;         // wave id, [0, B_*NPAD)
    const int half = lane >> 5, sl = lane & 31;

    const int side = gw >= (B_ * NPAD / 2);      // 0=pos, 1=neg
    const int p2   = side ? gw - (B_ * NPAD / 2) : gw;
    const int b    = p2 / (NPAD / 2);
    const int slot = (p2 % (NPAD / 2)) * 2 + half;

    const int np    = npos[b];
    const int count = side ? (N_ - np) : np;
    const unsigned short* idxArr = side ? negIdx : posIdx;

    float4 v = make_float4(0.f, 0.f, 0.f, 0.f);
    if (slot < count) {
        const int n = idxArr[b * NPAD + slot];
        v = *(const float4*)(emb + ((size_t)(b * N_ + n)) * D_ + sl * 4);
    }
    float ss = v.x * v.x + v.y * v.y + v.z * v.z + v.w * v.w;
    #pragma unroll
    for (int off = 16; off; off >>= 1) ss += __shfl_xor(ss, off);   // within 32-half
    const float scale = 1.0f / fmaxf(sqrtf(ss), 1e-12f);

    // HW fp8 e4m3 convert, RNE, handles denormals (14% of elements are <2^-6)
    unsigned int pk = 0;
    pk = __builtin_amdgcn_cvt_pk_fp8_f32(v.x * scale, v.y * scale, pk, false);
    pk = __builtin_amdgcn_cvt_pk_fp8_f32(v.z * scale, v.w * scale, pk, true);

    unsigned int* dst = side ? Aneg_c : Apos_c;
    dst[(size_t)(b * NPAD + slot) * (D_ / 4) + sl] = pk;
}

// ---------- gemm(fp8) + hinge + block reduce + fused finalize ----------
// 256 thr / 4 waves, one 128x128 sim tile. K=128 fp8 = 16KB/side staged in one
// shot (global_load_lds w=16, XOR swizzle on global side). Early-exit pad
// tiles. Last block (atomic ticket) reduces Stile -> out.
__global__ __launch_bounds__(256, 3) void gemm_hinge_kernel(
    const unsigned char* __restrict__ Apos_c,
    const unsigned char* __restrict__ Aneg_c,
    const int* __restrict__ npos,
    float* __restrict__ Stile,   // [NBLK]
    int* __restrict__ counter,
    float* __restrict__ out)
{
    __shared__ unsigned char ldsA[128 * 128];   // 16 KiB
    __shared__ unsigned char ldsB[128 * 128];   // 16 KiB
    __shared__ float sred[4];
    __shared__ int lastFlag;

    const int t    = threadIdx.x;
    const int w    = t >> 6;
    const int lane = t & 63;
    const int tm = blockIdx.x, tn = blockIdx.y, b = blockIdx.z;

    const int np = npos[b];
    const int nn = N_ - np;
    const bool active = (tm * 128 < np) && (tn * 128 < nn);

    float tileSum = 0.f;
    if (active) {
        const char* gA = (const char*)(Apos_c + ((size_t)b * NPAD + (size_t)tm * 128) * D_);
        const char* gB = (const char*)(Aneg_c + ((size_t)b * NPAD + (size_t)tn * 128) * D_);
        auto lA = (__attribute__((address_space(3))) char*)ldsA;
        auto lB = (__attribute__((address_space(3))) char*)ldsB;

        #pragma unroll
        for (int it = 0; it < 4; ++it) {
            const int p   = it * 4096 + t * 16;          // linear LDS byte pos
            const int row = p >> 7;                      // 128 B per row
            const int c   = (p >> 4) & 7;                // 16B chunk within row
            const int goff = (row << 7) | ((c ^ (row & 7)) << 4);
            __builtin_amdgcn_global_load_lds(
                (const __attribute__((address_space(1))) void*)(gA + goff),
                (__attribute__((address_space(3))) void*)(lA + it * 4096 + w * 1024),
                16, 0, 0);
            __builtin_amdgcn_global_load_lds(
                (const __attribute__((address_space(1))) void*)(gB + goff),
                (__attribute__((address_space(3))) void*)(lB + it * 4096 + w * 1024),
                16, 0, 0);
        }
        __syncthreads();

        const int wm = w & 1, wn = w >> 1;     // wave -> 64x64 quadrant
        const int r = lane & 15, quad = lane >> 4;
        const int rx = r & 7;

        floatx4 acc[4][4] = {};
        #pragma unroll
        for (int ks = 0; ks < 4; ++ks) {
            long af[4], bf[4];
            // lane(r,quad) wants row bytes [ks*32+quad*8, +8): 16B-chunk
            // g16=ks*2+(quad>>1) xor-swizzled by row&7, 8B half = quad&1
            const int boff = (((ks * 2 + (quad >> 1)) ^ rx) << 4) + (quad & 1) * 8;
            #pragma unroll
            for (int i = 0; i < 4; ++i) {
                af[i] = *(const long*)(ldsA + (wm * 64 + i * 16 + r) * 128 + boff);
                bf[i] = *(const long*)(ldsB + (wn * 64 + i * 16 + r) * 128 + boff);
            }
            #pragma unroll
            for (int i = 0; i < 4; ++i)
                #pragma unroll
                for (int j = 0; j < 4; ++j)
                    acc[i][j] = __builtin_amdgcn_mfma_f32_16x16x32_fp8_fp8(
                        af[i], bf[j], acc[i][j], 0, 0, 0);
        }

        // hinge + full-tile sum (fragment-layout agnostic; zero rows add 0)
        float s = 0.f;
        #pragma unroll
        for (int i = 0; i < 4; ++i)
            #pragma unroll
            for (int j = 0; j < 4; ++j)
                #pragma unroll
                for (int k2 = 0; k2 < 4; ++k2)
                    s += fmaxf(acc[i][j][k2] - 0.15f, 0.f);

        #pragma unroll
        for (int off = 32; off; off >>= 1) s += __shfl_down(s, off);
        if (lane == 0) sred[w] = s;
        __syncthreads();
        tileSum = sred[0] + sred[1] + sred[2] + sred[3];
    }

    // ---- publish tile sum + ticket; last block finalizes ----
    if (t == 0) {
        atomicExch(&Stile[b * NTILE + tm * T_ + tn], tileSum);  // coherent store
        __threadfence();
        const int ticket = atomicAdd(counter, 1);
        lastFlag = (ticket == NBLK - 1);
    }
    __syncthreads();

    if (lastFlag && t < 64) {
        __threadfence();
        const int bb = t;                     // one lane per batch
        float S = 0.f;
        #pragma unroll
        for (int k = 0; k < NTILE; ++k)
            S += atomicAdd(&Stile[bb * NTILE + k], 0.f);   // coherent read
        const int np2 = npos[bb];
        const int nn2 = N_ - np2;
        const bool valid = (np2 > 0) && (nn2 > 0);
        float ls = valid ? S / (float)max(nn2, 1) : 0.f;
        float c  = valid ? (float)np2 : 0.f;
        #pragma unroll
        for (int off = 32; off; off >>= 1) {
            ls += __shfl_down(ls, off);
            c  += __shfl_down(c, off);
        }
        if (t == 0) out[0] = ls / fmaxf(c, 1.f);
    }
}

extern "C" void kernel_launch(void* const* d_in, const int* in_sizes, int n_in,
                              void* d_out, int out_size, void* d_ws, size_t ws_size,
                              hipStream_t stream)
{
    const float*     emb = (const float*)d_in[0];
    const long long* lab = (const long long*)d_in[1];
    float* out = (float*)d_out;

    char* ws = (char*)d_ws;
    float* Stile = (float*)ws;                            // NBLK f32 (16 KiB pad)
    int*   npos  = (int*)(ws + (16 << 10));               // 64 i32
    int*   counter = (int*)(ws + (20 << 10));             // 1 i32
    unsigned short* posIdx = (unsigned short*)(ws + (32 << 10));   // 80 KiB
    unsigned short* negIdx = (unsigned short*)(ws + (160 << 10));  // 80 KiB
    unsigned int* Apos_c = (unsigned int*)(ws + (1 << 20));        // 5.25 MiB fp8
    unsigned int* Aneg_c = Apos_c + (size_t)B_ * NPAD * (D_ / 4);  // 5.25 MiB

    scan_kernel<<<B_, 256, 0, stream>>>(lab, posIdx, negIdx, npos, counter);

    prep_kernel<<<B_ * NPAD / 4, 256, 0, stream>>>(
        emb, posIdx, negIdx, npos, Apos_c, Aneg_c);

    dim3 grid(T_, T_, B_);
    gemm_hinge_kernel<<<grid, 256, 0, stream>>>(
        (const unsigned char*)Apos_c, (const unsigned char*)Aneg_c,
        npos, Stile, counter, out);
}

// Round 5
// 92.088 us; speedup vs baseline: 1.4700x; 1.4700x over previous
//
#include <hip/hip_runtime.h>
#include <stdint.h>

// ContrastiveLoss: B=64, N=1024, D=128.
// loss = (1/count) * sum_b valid_b * sum_{i pos} mean_{j neg} relu(<e_i,e_j> - 0.15)
//
// R4 lesson: atomic-ticket finalize fusion cost ~55us (1600 same-line
// device atomics serialize at ~21ns each; R1 pathology re-introduced).
// R5 = R3 structure (zero atomics, 4 dispatches) + R4's verified fp8-e4m3
// staging (absmax 7.6e-6, 4x under threshold) + early-exit pad tiles.
// Pipeline: scan -> prep(gather,fp8) -> gemm -> finalize.

#define B_    64
#define N_    1024
#define D_    128
#define NPAD  640          // 5 tiles of 128; npos~Binom(1024,.5), 640 = +8 sigma
#define T_    5            // tiles per side
#define NTILE (T_ * T_)

typedef __attribute__((ext_vector_type(4))) float floatx4;

// ---------- scan: per-batch prefix sums of labels -> compaction maps ----------
__global__ __launch_bounds__(256) void scan_kernel(
    const long long* __restrict__ lab,
    unsigned short* __restrict__ posIdx,   // [B_][NPAD]
    unsigned short* __restrict__ negIdx,   // [B_][NPAD]
    int* __restrict__ npos)                // [B_]
{
    __shared__ int wsum[4];
    const int b = blockIdx.x, t = threadIdx.x;
    const int w = t >> 6, lane = t & 63;
    const long long* lb = lab + (size_t)b * N_;

    int l[4], c = 0;
    #pragma unroll
    for (int i = 0; i < 4; ++i) { l[i] = (int)lb[t * 4 + i]; c += l[i]; }

    int sc = c;                              // inclusive wave scan
    #pragma unroll
    for (int off = 1; off < 64; off <<= 1) {
        int v = __shfl_up(sc, off);
        if (lane >= off) sc += v;
    }
    if (lane == 63) wsum[w] = sc;
    __syncthreads();
    int base = 0;
    for (int k = 0; k < w; ++k) base += wsum[k];

    int pe = base + sc - c;                  // pos count in [0, t*4)
    #pragma unroll
    for (int i = 0; i < 4; ++i) {
        const int n = t * 4 + i;
        if (l[i]) { if (pe < NPAD) posIdx[b * NPAD + pe] = (unsigned short)n; }
        else      { const int ne = n - pe; if (ne < NPAD) negIdx[b * NPAD + ne] = (unsigned short)n; }
        pe += l[i];
    }
    if (t == 255) npos[b] = base + sc;
}

// ---------- prep: gather + L2-normalize + fp8(e4m3, RNE) pack ----------
// One wave handles TWO slots (lanes 0-31 / 32-63), float4 loads, 4B fp8 out.
__global__ __launch_bounds__(256) void prep_kernel(
    const float* __restrict__ emb,
    const unsigned short* __restrict__ posIdx,
    const unsigned short* __restrict__ negIdx,
    const int* __restrict__ npos,
    unsigned int* __restrict__ Apos_c,       // [B_*NPAD*D_] fp8 as packed u32
    unsigned int* __restrict__ Aneg_c)
{
    const int w    = threadIdx.x >> 6;
    const int lane = threadIdx.x & 63;
    const int gw   = blockIdx.x * 4 + w;         // wave id, [0, B_*NPAD)
    const int half = lane >> 5, sl = lane & 31;

    const int side = gw >= (B_ * NPAD / 2);      // 0=pos, 1=neg
    const int p2   = side ? gw - (B_ * NPAD / 2) : gw;
    const int b    = p2 / (NPAD / 2);
    const int slot = (p2 % (NPAD / 2)) * 2 + half;

    const int np    = npos[b];
    const int count = side ? (N_ - np) : np;
    const unsigned short* idxArr = side ? negIdx : posIdx;

    float4 v = make_float4(0.f, 0.f, 0.f, 0.f);
    if (slot < count) {
        const int n = idxArr[b * NPAD + slot];
        v = *(const float4*)(emb + ((size_t)(b * N_ + n)) * D_ + sl * 4);
    }
    float ss = v.x * v.x + v.y * v.y + v.z * v.z + v.w * v.w;
    #pragma unroll
    for (int off = 16; off; off >>= 1) ss += __shfl_xor(ss, off);   // within 32-half
    const float scale = 1.0f / fmaxf(sqrtf(ss), 1e-12f);

    // HW fp8 e4m3 convert, RNE, handles denormals
    unsigned int pk = 0;
    pk = __builtin_amdgcn_cvt_pk_fp8_f32(v.x * scale, v.y * scale, pk, false);
    pk = __builtin_amdgcn_cvt_pk_fp8_f32(v.z * scale, v.w * scale, pk, true);

    unsigned int* dst = side ? Aneg_c : Apos_c;
    dst[(size_t)(b * NPAD + slot) * (D_ / 4) + sl] = pk;
}

// ---------- gemm(fp8) + hinge + block reduce (zero atomics) ----------
// 256 thr / 4 waves, one 128x128 sim tile. K=128 fp8 = 16KB/side staged in one
// shot (global_load_lds w=16, XOR swizzle on global side). Early-exit pad
// tiles. Plain store of the block's tile sum.
__global__ __launch_bounds__(256, 3) void gemm_hinge_kernel(
    const unsigned char* __restrict__ Apos_c,
    const unsigned char* __restrict__ Aneg_c,
    const int* __restrict__ npos,
    float* __restrict__ Stile)   // [B_ * NTILE]
{
    __shared__ unsigned char ldsA[128 * 128];   // 16 KiB
    __shared__ unsigned char ldsB[128 * 128];   // 16 KiB
    __shared__ float sred[4];

    const int t    = threadIdx.x;
    const int w    = t >> 6;
    const int lane = t & 63;
    const int tm = blockIdx.x, tn = blockIdx.y, b = blockIdx.z;

    const int np = npos[b];
    const int nn = N_ - np;
    const bool active = (tm * 128 < np) && (tn * 128 < nn);

    float tileSum = 0.f;
    if (active) {
        const char* gA = (const char*)(Apos_c + ((size_t)b * NPAD + (size_t)tm * 128) * D_);
        const char* gB = (const char*)(Aneg_c + ((size_t)b * NPAD + (size_t)tn * 128) * D_);
        auto lA = (__attribute__((address_space(3))) char*)ldsA;
        auto lB = (__attribute__((address_space(3))) char*)ldsB;

        #pragma unroll
        for (int it = 0; it < 4; ++it) {
            const int p   = it * 4096 + t * 16;          // linear LDS byte pos
            const int row = p >> 7;                      // 128 B per row
            const int c   = (p >> 4) & 7;                // 16B chunk within row
            const int goff = (row << 7) | ((c ^ (row & 7)) << 4);
            __builtin_amdgcn_global_load_lds(
                (const __attribute__((address_space(1))) void*)(gA + goff),
                (__attribute__((address_space(3))) void*)(lA + it * 4096 + w * 1024),
                16, 0, 0);
            __builtin_amdgcn_global_load_lds(
                (const __attribute__((address_space(1))) void*)(gB + goff),
                (__attribute__((address_space(3))) void*)(lB + it * 4096 + w * 1024),
                16, 0, 0);
        }
        __syncthreads();

        const int wm = w & 1, wn = w >> 1;     // wave -> 64x64 quadrant
        const int r = lane & 15, quad = lane >> 4;
        const int rx = r & 7;

        floatx4 acc[4][4] = {};
        #pragma unroll
        for (int ks = 0; ks < 4; ++ks) {
            long af[4], bf[4];
            // lane(r,quad) wants row bytes [ks*32+quad*8, +8): 16B-chunk
            // g16=ks*2+(quad>>1) xor-swizzled by row&7, 8B half = quad&1
            const int boff = (((ks * 2 + (quad >> 1)) ^ rx) << 4) + (quad & 1) * 8;
            #pragma unroll
            for (int i = 0; i < 4; ++i) {
                af[i] = *(const long*)(ldsA + (wm * 64 + i * 16 + r) * 128 + boff);
                bf[i] = *(const long*)(ldsB + (wn * 64 + i * 16 + r) * 128 + boff);
            }
            #pragma unroll
            for (int i = 0; i < 4; ++i)
                #pragma unroll
                for (int j = 0; j < 4; ++j)
                    acc[i][j] = __builtin_amdgcn_mfma_f32_16x16x32_fp8_fp8(
                        af[i], bf[j], acc[i][j], 0, 0, 0);
        }

        // hinge + full-tile sum (fragment-layout agnostic; zero rows add 0)
        float s = 0.f;
        #pragma unroll
        for (int i = 0; i < 4; ++i)
            #pragma unroll
            for (int j = 0; j < 4; ++j)
                #pragma unroll
                for (int k2 = 0; k2 < 4; ++k2)
                    s += fmaxf(acc[i][j][k2] - 0.15f, 0.f);

        #pragma unroll
        for (int off = 32; off; off >>= 1) s += __shfl_down(s, off);
        if (lane == 0) sred[w] = s;
        __syncthreads();
        tileSum = sred[0] + sred[1] + sred[2] + sred[3];
    }

    if (t == 0) Stile[b * NTILE + tm * T_ + tn] = tileSum;
}

// ---------- finalize: one wave does everything ----------
__global__ void finalize_kernel(const float* __restrict__ Stile,
                                const int* __restrict__ npos,
                                float* __restrict__ out)
{
    const int b = threadIdx.x;      // 64 threads = 1 wave
    const int np = npos[b];
    const int nn = N_ - np;
    float S = 0.f;
    #pragma unroll
    for (int k = 0; k < NTILE; ++k) S += Stile[b * NTILE + k];
    const bool valid = (np > 0) && (nn > 0);
    float ls = valid ? S / (float)nn : 0.f;
    float c  = valid ? (float)np : 0.f;
    #pragma unroll
    for (int off = 32; off; off >>= 1) {
        ls += __shfl_down(ls, off);
        c  += __shfl_down(c, off);
    }
    if (b == 0) out[0] = ls / fmaxf(c, 1.f);
}

extern "C" void kernel_launch(void* const* d_in, const int* in_sizes, int n_in,
                              void* d_out, int out_size, void* d_ws, size_t ws_size,
                              hipStream_t stream)
{
    const float*     emb = (const float*)d_in[0];
    const long long* lab = (const long long*)d_in[1];
    float* out = (float*)d_out;

    char* ws = (char*)d_ws;
    float* Stile = (float*)ws;                            // B_*NTILE f32
    int*   npos  = (int*)(ws + (16 << 10));               // 64 i32
    unsigned short* posIdx = (unsigned short*)(ws + (32 << 10));   // 80 KiB
    unsigned short* negIdx = (unsigned short*)(ws + (160 << 10));  // 80 KiB
    unsigned int* Apos_c = (unsigned int*)(ws + (1 << 20));        // 5.25 MiB fp8
    unsigned int* Aneg_c = Apos_c + (size_t)B_ * NPAD * (D_ / 4);  // 5.25 MiB

    scan_kernel<<<B_, 256, 0, stream>>>(lab, posIdx, negIdx, npos);

    prep_kernel<<<B_ * NPAD / 4, 256, 0, stream>>>(
        emb, posIdx, negIdx, npos, Apos_c, Aneg_c);

    dim3 grid(T_, T_, B_);
    gemm_hinge_kernel<<<grid, 256, 0, stream>>>(
        (const unsigned char*)Apos_c, (const unsigned char*)Aneg_c, npos, Stile);

    finalize_kernel<<<1, 64, 0, stream>>>(Stile, npos, out);
}

// Round 6
// 90.105 us; speedup vs baseline: 1.5023x; 1.0220x over previous
//
#include <hip/hip_runtime.h>
#include <stdint.h>

// ContrastiveLoss: B=64, N=1024, D=128.
// loss = (1/count) * sum_b valid_b * sum_{i pos} mean_{j neg} relu(<e_i,e_j> - 0.15)
//
// R5 lesson: ~57us of dur is harness (ws poison fill + input restore);
// kernel budget ~35us vs ~22us mandatory. R6: fold the label scan INTO the
// prep kernel (redundant per-block scan; labels are L2-resident, 8 blocks/
// batch x 8KB = 4MB L2 reads replaces a dispatch) and keep compaction maps
// in LDS only. 3 dispatches: prepscan -> gemm -> finalize. gemm/finalize
// are byte-identical to the R5-verified versions (absmax 7.6e-6).

#define B_    64
#define N_    1024
#define D_    128
#define NPAD  640          // 5 tiles of 128; npos~Binom(1024,.5)=512+-16, 640=+8sigma
#define T_    5            // tiles per side
#define NTILE (T_ * T_)
#define PBLK  8            // prep blocks per batch
#define SLOTS_PER_BLK (2 * NPAD / PBLK)   // 160 slots (both sides)

typedef __attribute__((ext_vector_type(4))) float floatx4;

// ---------- prepscan: in-block label scan + gather + normalize + fp8 pack ----
// Block: 1024 threads (16 waves). Phase 1: inclusive scan of this batch's
// 1024 labels -> compaction maps in LDS. Phase 2: each half-wave gathers one
// row (float4/lane), L2-normalizes, converts to fp8-e4m3 (HW RNE), stores.
__global__ __launch_bounds__(1024) void prepscan_kernel(
    const float* __restrict__ emb,
    const long long* __restrict__ lab,
    unsigned int* __restrict__ Apos_c,       // [B_*NPAD*D_/4] fp8 packed u32
    unsigned int* __restrict__ Aneg_c,
    int* __restrict__ npos)                  // [B_]
{
    __shared__ int wsum[16];
    __shared__ unsigned short posLds[NPAD];
    __shared__ unsigned short negLds[NPAD];

    const int t = threadIdx.x, w = t >> 6, lane = t & 63;
    const int b = blockIdx.y;

    // ---- phase 1: scan (redundant per block; labels hit L2) ----
    const int l = (int)lab[(size_t)b * N_ + t];
    int sc = l;
    #pragma unroll
    for (int off = 1; off < 64; off <<= 1) {
        int v = __shfl_up(sc, off);
        if (lane >= off) sc += v;
    }
    if (lane == 63) wsum[w] = sc;
    __syncthreads();
    int base = 0, tot = 0;
    #pragma unroll
    for (int k = 0; k < 16; ++k) {
        const int v = wsum[k];
        tot += v;
        if (k < w) base += v;
    }
    const int ep = base + sc - l;            // #pos strictly before t
    if (l) { if (ep < NPAD) posLds[ep] = (unsigned short)t; }
    else   { const int ne = t - ep; if (ne < NPAD) negLds[ne] = (unsigned short)t; }
    const int np = tot;
    if (blockIdx.x == 0 && t == 0) npos[b] = np;
    __syncthreads();

    // ---- phase 2: gather + normalize + fp8 ----
    const int half = lane >> 5, sl = lane & 31;
    #pragma unroll
    for (int it = 0; it < 5; ++it) {
        const int g    = blockIdx.x * SLOTS_PER_BLK + it * 32 + ((w << 1) | half);
        const int side = (g >= NPAD);        // 0=pos, 1=neg
        const int slot = g - (side ? NPAD : 0);
        const int count = side ? (N_ - np) : np;

        float4 v = make_float4(0.f, 0.f, 0.f, 0.f);
        if (slot < count) {
            const int n = side ? negLds[slot] : posLds[slot];   // broadcast read
            v = *(const float4*)(emb + ((size_t)(b * N_ + n)) * D_ + sl * 4);
        }
        float ss = v.x * v.x + v.y * v.y + v.z * v.z + v.w * v.w;
        #pragma unroll
        for (int off = 16; off; off >>= 1) ss += __shfl_xor(ss, off);  // 32-half
        const float scale = 1.0f / fmaxf(sqrtf(ss), 1e-12f);

        unsigned int pk = 0;
        pk = __builtin_amdgcn_cvt_pk_fp8_f32(v.x * scale, v.y * scale, pk, false);
        pk = __builtin_amdgcn_cvt_pk_fp8_f32(v.z * scale, v.w * scale, pk, true);

        unsigned int* dst = side ? Aneg_c : Apos_c;
        dst[(size_t)(b * NPAD + slot) * (D_ / 4) + sl] = pk;
    }
}

// ---------- gemm(fp8) + hinge + block reduce (zero atomics; R5-verified) ----
__global__ __launch_bounds__(256, 3) void gemm_hinge_kernel(
    const unsigned char* __restrict__ Apos_c,
    const unsigned char* __restrict__ Aneg_c,
    const int* __restrict__ npos,
    float* __restrict__ Stile)   // [B_ * NTILE]
{
    __shared__ unsigned char ldsA[128 * 128];   // 16 KiB
    __shared__ unsigned char ldsB[128 * 128];   // 16 KiB
    __shared__ float sred[4];

    const int t    = threadIdx.x;
    const int w    = t >> 6;
    const int lane = t & 63;
    const int tm = blockIdx.x, tn = blockIdx.y, b = blockIdx.z;

    const int np = npos[b];
    const int nn = N_ - np;
    const bool active = (tm * 128 < np) && (tn * 128 < nn);

    float tileSum = 0.f;
    if (active) {
        const char* gA = (const char*)(Apos_c + ((size_t)b * NPAD + (size_t)tm * 128) * D_);
        const char* gB = (const char*)(Aneg_c + ((size_t)b * NPAD + (size_t)tn * 128) * D_);
        auto lA = (__attribute__((address_space(3))) char*)ldsA;
        auto lB = (__attribute__((address_space(3))) char*)ldsB;

        #pragma unroll
        for (int it = 0; it < 4; ++it) {
            const int p   = it * 4096 + t * 16;          // linear LDS byte pos
            const int row = p >> 7;                      // 128 B per row
            const int c   = (p >> 4) & 7;                // 16B chunk within row
            const int goff = (row << 7) | ((c ^ (row & 7)) << 4);
            __builtin_amdgcn_global_load_lds(
                (const __attribute__((address_space(1))) void*)(gA + goff),
                (__attribute__((address_space(3))) void*)(lA + it * 4096 + w * 1024),
                16, 0, 0);
            __builtin_amdgcn_global_load_lds(
                (const __attribute__((address_space(1))) void*)(gB + goff),
                (__attribute__((address_space(3))) void*)(lB + it * 4096 + w * 1024),
                16, 0, 0);
        }
        __syncthreads();

        const int wm = w & 1, wn = w >> 1;     // wave -> 64x64 quadrant
        const int r = lane & 15, quad = lane >> 4;
        const int rx = r & 7;

        floatx4 acc[4][4] = {};
        #pragma unroll
        for (int ks = 0; ks < 4; ++ks) {
            long af[4], bf[4];
            const int boff = (((ks * 2 + (quad >> 1)) ^ rx) << 4) + (quad & 1) * 8;
            #pragma unroll
            for (int i = 0; i < 4; ++i) {
                af[i] = *(const long*)(ldsA + (wm * 64 + i * 16 + r) * 128 + boff);
                bf[i] = *(const long*)(ldsB + (wn * 64 + i * 16 + r) * 128 + boff);
            }
            #pragma unroll
            for (int i = 0; i < 4; ++i)
                #pragma unroll
                for (int j = 0; j < 4; ++j)
                    acc[i][j] = __builtin_amdgcn_mfma_f32_16x16x32_fp8_fp8(
                        af[i], bf[j], acc[i][j], 0, 0, 0);
        }

        float s = 0.f;
        #pragma unroll
        for (int i = 0; i < 4; ++i)
            #pragma unroll
            for (int j = 0; j < 4; ++j)
                #pragma unroll
                for (int k2 = 0; k2 < 4; ++k2)
                    s += fmaxf(acc[i][j][k2] - 0.15f, 0.f);

        #pragma unroll
        for (int off = 32; off; off >>= 1) s += __shfl_down(s, off);
        if (lane == 0) sred[w] = s;
        __syncthreads();
        tileSum = sred[0] + sred[1] + sred[2] + sred[3];
    }

    if (t == 0) Stile[b * NTILE + tm * T_ + tn] = tileSum;
}

// ---------- finalize: one wave does everything ----------
__global__ void finalize_kernel(const float* __restrict__ Stile,
                                const int* __restrict__ npos,
                                float* __restrict__ out)
{
    const int b = threadIdx.x;      // 64 threads = 1 wave
    const int np = npos[b];
    const int nn = N_ - np;
    float S = 0.f;
    #pragma unroll
    for (int k = 0; k < NTILE; ++k) S += Stile[b * NTILE + k];
    const bool valid = (np > 0) && (nn > 0);
    float ls = valid ? S / (float)nn : 0.f;
    float c  = valid ? (float)np : 0.f;
    #pragma unroll
    for (int off = 32; off; off >>= 1) {
        ls += __shfl_down(ls, off);
        c  += __shfl_down(c, off);
    }
    if (b == 0) out[0] = ls / fmaxf(c, 1.f);
}

extern "C" void kernel_launch(void* const* d_in, const int* in_sizes, int n_in,
                              void* d_out, int out_size, void* d_ws, size_t ws_size,
                              hipStream_t stream)
{
    const float*     emb = (const float*)d_in[0];
    const long long* lab = (const long long*)d_in[1];
    float* out = (float*)d_out;

    char* ws = (char*)d_ws;
    float* Stile = (float*)ws;                            // B_*NTILE f32
    int*   npos  = (int*)(ws + (16 << 10));               // 64 i32
    unsigned int* Apos_c = (unsigned int*)(ws + (1 << 20));        // 5.25 MiB fp8
    unsigned int* Aneg_c = Apos_c + (size_t)B_ * NPAD * (D_ / 4);  // 5.25 MiB

    dim3 pgrid(PBLK, B_);
    prepscan_kernel<<<pgrid, 1024, 0, stream>>>(emb, lab, Apos_c, Aneg_c, npos);

    dim3 grid(T_, T_, B_);
    gemm_hinge_kernel<<<grid, 256, 0, stream>>>(
        (const unsigned char*)Apos_c, (const unsigned char*)Aneg_c, npos, Stile);

    finalize_kernel<<<1, 64, 0, stream>>>(Stile, npos, out);
}